// Round 6
// baseline (86.233 us; speedup 1.0000x reference)
//
#include <hip/hip_runtime.h>
#include <hip/hip_bf16.h>

typedef unsigned short u16;
typedef __attribute__((ext_vector_type(8))) short short8;    // 8 bf16 = 4 VGPRs
typedef __attribute__((ext_vector_type(4))) float floatx4;   // 16x16 MFMA acc
typedef __attribute__((ext_vector_type(16))) float floatx16; // 32x32 MFMA acc
typedef __attribute__((ext_vector_type(4))) unsigned uint4v;

struct __attribute__((aligned(8))) u16x4 { u16 x, y, z, w; };
struct __attribute__((aligned(16))) u16x8 { u16 v[8]; };

__device__ __forceinline__ u16 f2bf(float f) {
  unsigned u = __builtin_bit_cast(unsigned, f);
  u += 0x7fff + ((u >> 16) & 1);   // RNE
  return (u16)(u >> 16);
}

__device__ __forceinline__ unsigned cvt_pk_bf16(float lo, float hi) {
  unsigned d;
  asm("v_cvt_pk_bf16_f32 %0, %1, %2" : "=v"(d) : "v"(lo), "v"(hi));
  return d;
}

// direct L2->LDS DMA, 16B/lane. LDS dest = wave-uniform base + lane*16 (linear).
__device__ __forceinline__ void gload_lds16(const u16* g, u16* l) {
  __builtin_amdgcn_global_load_lds(
      (const __attribute__((address_space(1))) void*)g,
      (__attribute__((address_space(3))) void*)l, 16, 0, 0);
}

// ---------------- weight fp32 -> bf16 ----------------
__global__ __launch_bounds__(256) void k_convert(
    const float* __restrict__ wq, const float* __restrict__ wp,
    u16* __restrict__ oq, u16* __restrict__ op) {
  int t = blockIdx.x * 256 + threadIdx.x;
  constexpr int NQ4 = (1536 * 512) / 4;
  constexpr int NP4 = (512 * 512) / 4;
  if (t < NQ4) {
    float4 v = reinterpret_cast<const float4*>(wq)[t];
    u16x4 o = { f2bf(v.x), f2bf(v.y), f2bf(v.z), f2bf(v.w) };
    reinterpret_cast<u16x4*>(oq)[t] = o;
  } else if (t - NQ4 < NP4) {
    int i = t - NQ4;
    float4 v = reinterpret_cast<const float4*>(wp)[i];
    u16x4 o = { f2bf(v.x), f2bf(v.y), f2bf(v.z), f2bf(v.w) };
    reinterpret_cast<u16x4*>(op)[i] = o;
  }
}

// ---------------- GroupNorm stats (deterministic partials) ----------------
__global__ __launch_bounds__(256) void k_gn_stats(const float* __restrict__ x,
                                                  float* __restrict__ stats) {
  int bg = blockIdx.x >> 3, sl = blockIdx.x & 7;
  int b = bg >> 3, g = bg & 7;
  const float* base = x + ((size_t)(b * 512 + g * 64) * 1024) + sl * 128;
  float s = 0.f, ss = 0.f;
#pragma unroll
  for (int i = 0; i < 8; ++i) {
    int idx = threadIdx.x + i * 256;
    int c = idx >> 5, l4 = idx & 31;
    float4 v = *reinterpret_cast<const float4*>(base + (size_t)c * 1024 + l4 * 4);
    s += v.x + v.y + v.z + v.w;
    ss += v.x * v.x + v.y * v.y + v.z * v.z + v.w * v.w;
  }
#pragma unroll
  for (int d = 1; d < 64; d <<= 1) { s += __shfl_xor(s, d); ss += __shfl_xor(ss, d); }
  __shared__ float rs[4], rss[4];
  int wid = threadIdx.x >> 6;
  if ((threadIdx.x & 63) == 0) { rs[wid] = s; rss[wid] = ss; }
  __syncthreads();
  if (threadIdx.x == 0) {
    stats[(bg * 8 + sl) * 2]     = rs[0] + rs[1] + rs[2] + rs[3];
    stats[(bg * 8 + sl) * 2 + 1] = rss[0] + rss[1] + rss[2] + rss[3];
  }
}

// ---------------- GroupNorm normalize + transpose to xnT [b][l][c] bf16 ----------------
__global__ __launch_bounds__(256) void k_gn_norm(
    const float* __restrict__ x, const float* __restrict__ gamma,
    const float* __restrict__ beta, const float* __restrict__ stats,
    u16* __restrict__ xnT) {
  int bg = blockIdx.x >> 3, sl = blockIdx.x & 7;
  int b = bg >> 3, g = bg & 7;
  float s = 0.f, ss = 0.f;
#pragma unroll
  for (int i = 0; i < 8; ++i) { s += stats[(bg * 8 + i) * 2]; ss += stats[(bg * 8 + i) * 2 + 1]; }
  const float inv_n = 1.0f / 65536.0f;
  float mean = s * inv_n;
  float var = ss * inv_n - mean * mean;
  float istd = rsqrtf(var + 1e-5f);
  __shared__ float tile[128 * 65];
  const float* base = x + ((size_t)(b * 512 + g * 64) * 1024) + sl * 128;
#pragma unroll
  for (int i = 0; i < 8; ++i) {
    int idx = threadIdx.x + i * 256;
    int c = idx >> 5, l4 = idx & 31;
    float4 v = *reinterpret_cast<const float4*>(base + (size_t)c * 1024 + l4 * 4);
    float gm = gamma[g * 64 + c];
    float ga = gm * istd;
    float be = beta[g * 64 + c] - mean * ga;
    tile[(l4 * 4 + 0) * 65 + c] = v.x * ga + be;
    tile[(l4 * 4 + 1) * 65 + c] = v.y * ga + be;
    tile[(l4 * 4 + 2) * 65 + c] = v.z * ga + be;
    tile[(l4 * 4 + 3) * 65 + c] = v.w * ga + be;
  }
  __syncthreads();
  u16* obase = xnT + ((size_t)(b * 1024 + sl * 128) * 512) + g * 64;
#pragma unroll
  for (int i = 0; i < 8; ++i) {
    int idx = threadIdx.x + i * 256;
    int l = idx >> 4, c4 = (idx & 15) * 4;
    u16x4 o = { f2bf(tile[l * 65 + c4]),     f2bf(tile[l * 65 + c4 + 1]),
                f2bf(tile[l * 65 + c4 + 2]), f2bf(tile[l * 65 + c4 + 3]) };
    *reinterpret_cast<u16x4*>(obase + (size_t)l * 512 + c4) = o;
  }
}

// ---------------- GEMM: double-buffered gload_lds + counted vmcnt + LDS epilogue ------
// MODE 0: M=1536 -> Q/K [b][l][512], V [b][512][l] bf16 (+bias, Q pre-scaled)
// MODE 1: M=512  -> fp32 [b][512][1024] = acc + bias + x (residual)
template <int MODE>
__global__ __launch_bounds__(256) void k_gemm(
    const u16* __restrict__ A, const u16* __restrict__ Bm,
    const float* __restrict__ bias, const float* __restrict__ xres,
    u16* __restrict__ Qb, u16* __restrict__ Kb, u16* __restrict__ Vb,
    float* __restrict__ out) {
  // XCD-chunked swizzle (grid%8==0): each XCD owns one b's panel set.
  int b = blockIdx.x & 7;
  int rem = blockIdx.x >> 3;           // [0, MT*8)
  int mt = rem >> 3, nt = rem & 7;
  int tid = threadIdx.x;
  int lane = tid & 63, wid = tid >> 6;
  int wm = wid >> 1, wn = wid & 1;

  union SM {
    u16 ab[2][2][128 * 64];   // [buf][A/B][row*64+chunk] : 64 KB
    u16 c16[128 * 136];       // epilogue bf16 tile, pitch 136
    float c32[128 * 128];     // epilogue fp32 tile, pitch 128 (=64 KB)
  };
  __shared__ SM sm;

  floatx4 z = {0.f, 0.f, 0.f, 0.f};
  floatx4 acc[4][4];
#pragma unroll
  for (int m = 0; m < 4; ++m)
#pragma unroll
    for (int n = 0; n < 4; ++n) acc[m][n] = z;

  const u16* Abase = A + (size_t)(mt * 128) * 512;
  const u16* Bbase = Bm + ((size_t)(b * 1024 + nt * 128)) * 512;
  // pre-swizzled source: lane loads chunk (lane&7)^(lane>>3) of row (wid*32+j*8+(lane>>3));
  // linear LDS dest then holds swizzled layout the read side expects.
  int cb0 = (lane & 7) ^ (lane >> 3);
  const u16* asrc = Abase + (size_t)(wid * 32 + (lane >> 3)) * 512 + cb0 * 8;
  const u16* bsrc = Bbase + (size_t)(wid * 32 + (lane >> 3)) * 512 + cb0 * 8;

#define STAGE(BUF, KK)                                                           \
  {                                                                              \
    _Pragma("unroll")                                                            \
    for (int j = 0; j < 4; ++j) {                                                \
      gload_lds16(asrc + (size_t)j * 8 * 512 + (KK) * 64,                        \
                  &sm.ab[BUF][0][wid * 2048 + j * 512]);                         \
      gload_lds16(bsrc + (size_t)j * 8 * 512 + (KK) * 64,                        \
                  &sm.ab[BUF][1][wid * 2048 + j * 512]);                         \
    }                                                                            \
  }

  STAGE(0, 0);   // prologue: tile 0 in flight (8 insts/wave)
#pragma unroll
  for (int kk = 0; kk < 8; ++kk) {
    const int cur = kk & 1;
    if (kk < 7) {
      STAGE(cur ^ 1, kk + 1);                       // prefetch next tile (8 more in flight)
      asm volatile("s_waitcnt vmcnt(8)" ::: "memory");  // current tile's 8 done; prefetch stays in flight
    } else {
      asm volatile("s_waitcnt vmcnt(0)" ::: "memory");
    }
    __builtin_amdgcn_s_barrier();
    __builtin_amdgcn_sched_barrier(0);
    const u16* Asc = sm.ab[cur][0];
    const u16* Bsc = sm.ab[cur][1];
#pragma unroll
    for (int kc = 0; kc < 2; ++kc) {
      int cbk = kc * 4 + (lane >> 4);
      short8 af[4], bf[4];
#pragma unroll
      for (int m = 0; m < 4; ++m) {
        int row = wm * 64 + m * 16 + (lane & 15);
        af[m] = *reinterpret_cast<const short8*>(Asc + row * 64 + ((cbk ^ (row & 7)) * 8));
      }
#pragma unroll
      for (int n = 0; n < 4; ++n) {
        int row = wn * 64 + n * 16 + (lane & 15);
        bf[n] = *reinterpret_cast<const short8*>(Bsc + row * 64 + ((cbk ^ (row & 7)) * 8));
      }
#pragma unroll
      for (int m = 0; m < 4; ++m)
#pragma unroll
        for (int n = 0; n < 4; ++n)
          acc[m][n] = __builtin_amdgcn_mfma_f32_16x16x32_bf16(af[m], bf[n], acc[m][n], 0, 0, 0);
    }
    __builtin_amdgcn_s_barrier();   // all waves done reading buf[cur]; safe to DMA into it next iter
  }
#undef STAGE

  // ---------------- epilogue: stage C-tile in LDS, write coalesced 256B rows ----------
  int sec = (MODE == 0) ? (mt >> 2) : 0;       // 0=Q 1=K 2=V (uniform per block)
  int ow0 = (mt & 3) * 128;
#pragma unroll
  for (int m = 0; m < 4; ++m) {
#pragma unroll
    for (int n = 0; n < 4; ++n) {
#pragma unroll
      for (int r = 0; r < 4; ++r) {
        int o_l = wm * 64 + m * 16 + ((lane >> 4) * 4) + r;   // local out-row
        int l_l = wn * 64 + n * 16 + (lane & 15);             // local l
        float v = acc[m][n][r] + bias[mt * 128 + o_l];
        if (MODE == 0) {
          if (sec == 0) v *= 0.18033688f;   // 0.125 * log2(e): scores in exp2 domain
          u16 bv = f2bf(v);
          if (sec < 2) sm.c16[l_l * 136 + o_l] = bv;   // Q/K: [l][o]
          else         sm.c16[o_l * 136 + l_l] = bv;   // V:   [o][l]
        } else {
          sm.c32[o_l * 128 + l_l] = v;                 // proj: [o][l]
        }
      }
    }
  }
  __syncthreads();
  if (MODE == 0) {
    u16* dst = (sec == 0) ? Qb : (sec == 1 ? Kb : Vb);
#pragma unroll
    for (int p = 0; p < 8; ++p) {
      int row = p * 16 + (tid >> 4);        // 16 rows per pass
      int col = (tid & 15) * 8;             // 16 lanes x 16B = 256B contiguous per row
      u16x8 vv = *reinterpret_cast<const u16x8*>(&sm.c16[row * 136 + col]);
      size_t gi;
      if (sec < 2) gi = ((size_t)(b * 1024 + nt * 128 + row)) * 512 + ow0 + col;
      else         gi = ((size_t)(b * 512 + ow0 + row)) * 1024 + nt * 128 + col;
      *reinterpret_cast<u16x8*>(dst + gi) = vv;
    }
  } else {
#pragma unroll
    for (int p = 0; p < 16; ++p) {
      int row = p * 8 + (tid >> 5);         // 8 rows per pass
      int col = (tid & 31) * 4;             // 32 lanes x 16B = 512B contiguous per row
      float4 vv = *reinterpret_cast<const float4*>(&sm.c32[row * 128 + col]);
      size_t gi = ((size_t)(b * 512 + mt * 128 + row)) * 1024 + nt * 128 + col;
      float4 xr = *reinterpret_cast<const float4*>(xres + gi);
      vv.x += xr.x; vv.y += xr.y; vv.z += xr.z; vv.w += xr.w;
      *reinterpret_cast<float4*>(out + gi) = vv;
    }
  }
}

// ---------------- flash attention, swapped-QK 32x32 in-register softmax ----------------
__global__ __launch_bounds__(256) void k_attn(
    const u16* __restrict__ Qb, const u16* __restrict__ Kb,
    const u16* __restrict__ Vb, u16* __restrict__ OT) {
  int b = blockIdx.x & 7;
  int h = (blockIdx.x >> 3) & 7;
  int qt = blockIdx.x >> 6;
  int tid = threadIdx.x;
  int lane = tid & 63, wid = tid >> 6;
  int l31 = lane & 31, g = lane >> 5;
  int r7 = l31 & 7;
  __shared__ u16 Ks[64 * 64], Vs[64 * 64];

  short8 qf[4];
  int qrow = qt * 128 + wid * 32 + l31;
  const u16* qp = Qb + ((size_t)(b * 1024 + qrow)) * 512 + h * 64 + g * 8;
#pragma unroll
  for (int kc2 = 0; kc2 < 4; ++kc2)
    qf[kc2] = *reinterpret_cast<const short8*>(qp + kc2 * 16);

  floatx16 oacc[2];
#pragma unroll
  for (int nd = 0; nd < 2; ++nd)
#pragma unroll
    for (int r = 0; r < 16; ++r) oacc[nd][r] = 0.f;
  float m = -1e30f, se = 0.f;

  const u16* ksrc[2]; const u16* vsrc[2]; int sdst[2];
#pragma unroll
  for (int i = 0; i < 2; ++i) {
    int idx = tid + i * 256;
    int row = idx >> 3, cb = idx & 7;
    ksrc[i] = Kb + ((size_t)(b * 1024 + row)) * 512 + h * 64 + cb * 8;
    vsrc[i] = Vb + ((size_t)(b * 512 + h * 64 + row)) * 1024 + cb * 8;
    sdst[i] = row * 64 + ((cb ^ (row & 7)) * 8);
  }
  short8 kreg[2], vreg[2];
#pragma unroll
  for (int i = 0; i < 2; ++i) {
    kreg[i] = *reinterpret_cast<const short8*>(ksrc[i]);
    vreg[i] = *reinterpret_cast<const short8*>(vsrc[i]);
  }

  for (int kt = 0; kt < 16; ++kt) {
#pragma unroll
    for (int i = 0; i < 2; ++i) {
      *reinterpret_cast<short8*>(Ks + sdst[i]) = kreg[i];
      *reinterpret_cast<short8*>(Vs + sdst[i]) = vreg[i];
    }
    __syncthreads();
    if (kt < 15) {
#pragma unroll
      for (int i = 0; i < 2; ++i) {
        kreg[i] = *reinterpret_cast<const short8*>(ksrc[i] + (size_t)(kt + 1) * 64 * 512);
        vreg[i] = *reinterpret_cast<const short8*>(vsrc[i] + (kt + 1) * 64);
      }
    }
    floatx16 sacc[2];
#pragma unroll
    for (int nk = 0; nk < 2; ++nk)
#pragma unroll
      for (int r = 0; r < 16; ++r) sacc[nk][r] = 0.f;
#pragma unroll
    for (int nk = 0; nk < 2; ++nk) {
      const u16* krow = Ks + (nk * 32 + l31) * 64;
#pragma unroll
      for (int kc2 = 0; kc2 < 4; ++kc2) {
        int cb = kc2 * 2 + g;
        short8 kf = *reinterpret_cast<const short8*>(krow + ((cb ^ r7) * 8));
        sacc[nk] = __builtin_amdgcn_mfma_f32_32x32x16_bf16(kf, qf[kc2], sacc[nk], 0, 0, 0);
      }
    }
    float pmax = sacc[0][0];
#pragma unroll
    for (int r = 1; r < 16; ++r) pmax = fmaxf(pmax, sacc[0][r]);
#pragma unroll
    for (int r = 0; r < 16; ++r) pmax = fmaxf(pmax, sacc[1][r]);
    pmax = fmaxf(pmax, __shfl_xor(pmax, 32));
    if (__any(pmax > m + 8.0f)) {      // defer-max
      float mn = fmaxf(m, pmax);
      float f = __builtin_amdgcn_exp2f(m - mn);
      m = mn;
      se *= f;
#pragma unroll
      for (int nd = 0; nd < 2; ++nd)
#pragma unroll
        for (int r = 0; r < 16; ++r) oacc[nd][r] *= f;
    }
    float sum = 0.f;
#pragma unroll
    for (int nk = 0; nk < 2; ++nk)
#pragma unroll
      for (int r = 0; r < 16; ++r) {
        float pv = __builtin_amdgcn_exp2f(sacc[nk][r] - m);
        sacc[nk][r] = pv;
        sum += pv;
      }
    sum += __shfl_xor(sum, 32);
    se += sum;
#pragma unroll
    for (int nk = 0; nk < 2; ++nk) {
#pragma unroll
      for (int kc = 0; kc < 2; ++kc) {
        int base = kc * 8;
        unsigned w0 = cvt_pk_bf16(sacc[nk][base + 0], sacc[nk][base + 1]);
        unsigned w2 = cvt_pk_bf16(sacc[nk][base + 4], sacc[nk][base + 5]);
        auto s0 = __builtin_amdgcn_permlane32_swap((int)w0, (int)w2, false, false);
        unsigned w1 = cvt_pk_bf16(sacc[nk][base + 2], sacc[nk][base + 3]);
        unsigned w3 = cvt_pk_bf16(sacc[nk][base + 6], sacc[nk][base + 7]);
        auto s1 = __builtin_amdgcn_permlane32_swap((int)w1, (int)w3, false, false);
        short8 pf = __builtin_bit_cast(short8,
            uint4v{(unsigned)s0[0], (unsigned)s1[0], (unsigned)s0[1], (unsigned)s1[1]});
#pragma unroll
        for (int nd = 0; nd < 2; ++nd) {
          const u16* vrow = Vs + (nd * 32 + l31) * 64;
          int cb = nk * 4 + kc * 2 + g;
          short8 vf = *reinterpret_cast<const short8*>(vrow + ((cb ^ r7) * 8));
          oacc[nd] = __builtin_amdgcn_mfma_f32_32x32x16_bf16(vf, pf, oacc[nd], 0, 0, 0);
        }
      }
    }
    __syncthreads();
  }
  float inv = 1.0f / se;
  u16* obase = OT + ((size_t)(b * 1024 + qrow)) * 512 + h * 64;
#pragma unroll
  for (int nd = 0; nd < 2; ++nd) {
#pragma unroll
    for (int rq = 0; rq < 4; ++rq) {
      u16x4 o = { f2bf(oacc[nd][rq * 4 + 0] * inv), f2bf(oacc[nd][rq * 4 + 1] * inv),
                  f2bf(oacc[nd][rq * 4 + 2] * inv), f2bf(oacc[nd][rq * 4 + 3] * inv) };
      *reinterpret_cast<u16x4*>(obase + nd * 32 + rq * 8 + g * 4) = o;
    }
  }
}

extern "C" void kernel_launch(void* const* d_in, const int* in_sizes, int n_in,
                              void* d_out, int out_size, void* d_ws, size_t ws_size,
                              hipStream_t stream) {
  const float* x      = (const float*)d_in[0];
  const float* gamma  = (const float*)d_in[1];
  const float* beta   = (const float*)d_in[2];
  const float* w_qkv  = (const float*)d_in[3];
  const float* b_qkv  = (const float*)d_in[4];
  const float* w_proj = (const float*)d_in[5];
  const float* b_proj = (const float*)d_in[6];
  float* out = (float*)d_out;

  char* ws = (char*)d_ws;
  size_t off = 0;
  float* stats = (float*)(ws + off); off += 4096;
  u16* wqb = (u16*)(ws + off); off += (size_t)1536 * 512 * 2;
  u16* wpb = (u16*)(ws + off); off += (size_t)512 * 512 * 2;
  u16* xnT = (u16*)(ws + off); off += (size_t)8 * 1024 * 512 * 2;
  u16* Qb  = (u16*)(ws + off); off += (size_t)8 * 1024 * 512 * 2;
  u16* Kb  = (u16*)(ws + off); off += (size_t)8 * 1024 * 512 * 2;
  u16* Vb  = (u16*)(ws + off); off += (size_t)8 * 1024 * 512 * 2;
  u16* OT  = (u16*)(ws + off); off += (size_t)8 * 1024 * 512 * 2;
  if (ws_size < off) return;

  k_convert<<<1024, 256, 0, stream>>>(w_qkv, w_proj, wqb, wpb);
  k_gn_stats<<<512, 256, 0, stream>>>(x, stats);
  k_gn_norm<<<512, 256, 0, stream>>>(x, gamma, beta, stats, xnT);
  k_gemm<0><<<768, 256, 0, stream>>>(wqb, xnT, b_qkv, nullptr, Qb, Kb, Vb, nullptr);
  k_attn<<<512, 256, 0, stream>>>(Qb, Kb, Vb, OT);
  k_gemm<1><<<256, 256, 0, stream>>>(wpb, OT, b_proj, x, nullptr, nullptr, nullptr, out);
}

// Round 7
// 85.678 us; speedup vs baseline: 1.0065x; 1.0065x over previous
//
#include <hip/hip_runtime.h>
#include <hip/hip_bf16.h>

typedef unsigned short u16;
typedef __attribute__((ext_vector_type(8))) short short8;    // 8 bf16 = 4 VGPRs
typedef __attribute__((ext_vector_type(4))) float floatx4;   // 16x16 MFMA acc
typedef __attribute__((ext_vector_type(16))) float floatx16; // 32x32 MFMA acc
typedef __attribute__((ext_vector_type(4))) unsigned uint4v;

struct __attribute__((aligned(8))) u16x4 { u16 x, y, z, w; };
struct __attribute__((aligned(16))) u16x8 { u16 v[8]; };

__device__ __forceinline__ u16 f2bf(float f) {
  unsigned u = __builtin_bit_cast(unsigned, f);
  u += 0x7fff + ((u >> 16) & 1);   // RNE
  return (u16)(u >> 16);
}

__device__ __forceinline__ unsigned cvt_pk_bf16(float lo, float hi) {
  unsigned d;
  asm("v_cvt_pk_bf16_f32 %0, %1, %2" : "=v"(d) : "v"(lo), "v"(hi));
  return d;
}

// direct L2->LDS DMA, 16B/lane. LDS dest = wave-uniform base + lane*16 (linear).
__device__ __forceinline__ void gload_lds16(const u16* g, u16* l) {
  __builtin_amdgcn_global_load_lds(
      (const __attribute__((address_space(1))) void*)g,
      (__attribute__((address_space(3))) void*)l, 16, 0, 0);
}

// ---------------- weight fp32 -> bf16 ----------------
__global__ __launch_bounds__(256) void k_convert(
    const float* __restrict__ wq, const float* __restrict__ wp,
    u16* __restrict__ oq, u16* __restrict__ op) {
  int t = blockIdx.x * 256 + threadIdx.x;
  constexpr int NQ4 = (1536 * 512) / 4;
  constexpr int NP4 = (512 * 512) / 4;
  if (t < NQ4) {
    float4 v = reinterpret_cast<const float4*>(wq)[t];
    u16x4 o = { f2bf(v.x), f2bf(v.y), f2bf(v.z), f2bf(v.w) };
    reinterpret_cast<u16x4*>(oq)[t] = o;
  } else if (t - NQ4 < NP4) {
    int i = t - NQ4;
    float4 v = reinterpret_cast<const float4*>(wp)[i];
    u16x4 o = { f2bf(v.x), f2bf(v.y), f2bf(v.z), f2bf(v.w) };
    reinterpret_cast<u16x4*>(op)[i] = o;
  }
}

// ---------------- GroupNorm stats (deterministic partials) ----------------
__global__ __launch_bounds__(256) void k_gn_stats(const float* __restrict__ x,
                                                  float* __restrict__ stats) {
  int bg = blockIdx.x >> 3, sl = blockIdx.x & 7;
  int b = bg >> 3, g = bg & 7;
  const float* base = x + ((size_t)(b * 512 + g * 64) * 1024) + sl * 128;
  float s = 0.f, ss = 0.f;
#pragma unroll
  for (int i = 0; i < 8; ++i) {
    int idx = threadIdx.x + i * 256;
    int c = idx >> 5, l4 = idx & 31;
    float4 v = *reinterpret_cast<const float4*>(base + (size_t)c * 1024 + l4 * 4);
    s += v.x + v.y + v.z + v.w;
    ss += v.x * v.x + v.y * v.y + v.z * v.z + v.w * v.w;
  }
#pragma unroll
  for (int d = 1; d < 64; d <<= 1) { s += __shfl_xor(s, d); ss += __shfl_xor(ss, d); }
  __shared__ float rs[4], rss[4];
  int wid = threadIdx.x >> 6;
  if ((threadIdx.x & 63) == 0) { rs[wid] = s; rss[wid] = ss; }
  __syncthreads();
  if (threadIdx.x == 0) {
    stats[(bg * 8 + sl) * 2]     = rs[0] + rs[1] + rs[2] + rs[3];
    stats[(bg * 8 + sl) * 2 + 1] = rss[0] + rss[1] + rss[2] + rss[3];
  }
}

// ---------------- GroupNorm normalize + transpose to xnT [b][l][c] bf16 ----------------
__global__ __launch_bounds__(256) void k_gn_norm(
    const float* __restrict__ x, const float* __restrict__ gamma,
    const float* __restrict__ beta, const float* __restrict__ stats,
    u16* __restrict__ xnT) {
  int bg = blockIdx.x >> 3, sl = blockIdx.x & 7;
  int b = bg >> 3, g = bg & 7;
  float s = 0.f, ss = 0.f;
#pragma unroll
  for (int i = 0; i < 8; ++i) { s += stats[(bg * 8 + i) * 2]; ss += stats[(bg * 8 + i) * 2 + 1]; }
  const float inv_n = 1.0f / 65536.0f;
  float mean = s * inv_n;
  float var = ss * inv_n - mean * mean;
  float istd = rsqrtf(var + 1e-5f);
  __shared__ float tile[128 * 65];
  const float* base = x + ((size_t)(b * 512 + g * 64) * 1024) + sl * 128;
#pragma unroll
  for (int i = 0; i < 8; ++i) {
    int idx = threadIdx.x + i * 256;
    int c = idx >> 5, l4 = idx & 31;
    float4 v = *reinterpret_cast<const float4*>(base + (size_t)c * 1024 + l4 * 4);
    float gm = gamma[g * 64 + c];
    float ga = gm * istd;
    float be = beta[g * 64 + c] - mean * ga;
    tile[(l4 * 4 + 0) * 65 + c] = v.x * ga + be;
    tile[(l4 * 4 + 1) * 65 + c] = v.y * ga + be;
    tile[(l4 * 4 + 2) * 65 + c] = v.z * ga + be;
    tile[(l4 * 4 + 3) * 65 + c] = v.w * ga + be;
  }
  __syncthreads();
  u16* obase = xnT + ((size_t)(b * 1024 + sl * 128) * 512) + g * 64;
#pragma unroll
  for (int i = 0; i < 8; ++i) {
    int idx = threadIdx.x + i * 256;
    int l = idx >> 4, c4 = (idx & 15) * 4;
    u16x4 o = { f2bf(tile[l * 65 + c4]),     f2bf(tile[l * 65 + c4 + 1]),
                f2bf(tile[l * 65 + c4 + 2]), f2bf(tile[l * 65 + c4 + 3]) };
    *reinterpret_cast<u16x4*>(obase + (size_t)l * 512 + c4) = o;
  }
}

// ---------------- GEMM: 8 waves/block, dbuf gload_lds, counted vmcnt, LDS epilogue ----
// MODE 0: M=1536 -> Q/K [b][l][512], V [b][512][l] bf16 (+bias, Q pre-scaled)
// MODE 1: M=512  -> fp32 [b][512][1024] = acc + bias + x (residual)
// 512 threads: wave wm=wid>>2 (2), wn=wid&3 (4); wave tile 64x32 (4x2 frags of 16x16).
template <int MODE>
__global__ __launch_bounds__(512) void k_gemm(
    const u16* __restrict__ A, const u16* __restrict__ Bm,
    const float* __restrict__ bias, const float* __restrict__ xres,
    u16* __restrict__ Qb, u16* __restrict__ Kb, u16* __restrict__ Vb,
    float* __restrict__ out) {
  // blockIdx&7 = b: with round-robin block->XCD, each XCD keeps one b's panels L2-hot.
  int b = blockIdx.x & 7;
  int rem = blockIdx.x >> 3;
  int mt = rem >> 3, nt = rem & 7;
  int tid = threadIdx.x;
  int lane = tid & 63, wid = tid >> 6;
  int wm = wid >> 2, wn = wid & 3;

  union SM {
    u16 ab[2][2][128 * 64];   // [buf][A/B][row*64+chunk] : 64 KB
    u16 c16[128 * 136];       // epilogue bf16 tile, pitch 136 (34.8 KB)
    float c32[128 * 128];     // epilogue fp32 tile, pitch 128 (64 KB)
  };
  __shared__ SM sm;

  floatx4 z = {0.f, 0.f, 0.f, 0.f};
  floatx4 acc[4][2];
#pragma unroll
  for (int m = 0; m < 4; ++m)
#pragma unroll
    for (int n = 0; n < 2; ++n) acc[m][n] = z;

  const u16* Abase = A + (size_t)(mt * 128) * 512;
  const u16* Bbase = Bm + ((size_t)(b * 1024 + nt * 128)) * 512;
  // pre-swizzled source: lane loads chunk (lane&7)^(lane>>3); linear LDS dest then
  // holds the swizzled layout the read side expects (slot sc holds chunk sc^(row&7)).
  int cb0 = (lane & 7) ^ (lane >> 3);
  const u16* asrc = Abase + (size_t)(wid * 16 + (lane >> 3)) * 512 + cb0 * 8;
  const u16* bsrc = Bbase + (size_t)(wid * 16 + (lane >> 3)) * 512 + cb0 * 8;

  // per wave: 2 A-insts + 2 B-insts = 4 gload_lds per K-step (16 rows each of A,B)
#define STAGE(BUF, KK)                                                           \
  {                                                                              \
    _Pragma("unroll")                                                            \
    for (int j = 0; j < 2; ++j) {                                                \
      gload_lds16(asrc + (size_t)j * 8 * 512 + (KK) * 64,                        \
                  &sm.ab[BUF][0][(wid * 16 + j * 8) * 64]);                      \
      gload_lds16(bsrc + (size_t)j * 8 * 512 + (KK) * 64,                        \
                  &sm.ab[BUF][1][(wid * 16 + j * 8) * 64]);                      \
    }                                                                            \
  }

  STAGE(0, 0);   // prologue: tile 0 in flight (4 insts/wave)
#pragma unroll
  for (int kk = 0; kk < 8; ++kk) {
    const int cur = kk & 1;
    if (kk < 7) {
      STAGE(cur ^ 1, kk + 1);                           // prefetch next tile
      asm volatile("s_waitcnt vmcnt(4)" ::: "memory");  // current tile done; prefetch in flight
    } else {
      asm volatile("s_waitcnt vmcnt(0)" ::: "memory");
    }
    __builtin_amdgcn_s_barrier();
    __builtin_amdgcn_sched_barrier(0);
    const u16* Asc = sm.ab[cur][0];
    const u16* Bsc = sm.ab[cur][1];
#pragma unroll
    for (int kc = 0; kc < 2; ++kc) {
      int cbk = kc * 4 + (lane >> 4);
      short8 af[4], bf[2];
#pragma unroll
      for (int m = 0; m < 4; ++m) {
        int row = wm * 64 + m * 16 + (lane & 15);
        af[m] = *reinterpret_cast<const short8*>(Asc + row * 64 + ((cbk ^ (row & 7)) * 8));
      }
#pragma unroll
      for (int n = 0; n < 2; ++n) {
        int row = wn * 32 + n * 16 + (lane & 15);
        bf[n] = *reinterpret_cast<const short8*>(Bsc + row * 64 + ((cbk ^ (row & 7)) * 8));
      }
      __builtin_amdgcn_s_setprio(1);
#pragma unroll
      for (int m = 0; m < 4; ++m)
#pragma unroll
        for (int n = 0; n < 2; ++n)
          acc[m][n] = __builtin_amdgcn_mfma_f32_16x16x32_bf16(af[m], bf[n], acc[m][n], 0, 0, 0);
      __builtin_amdgcn_s_setprio(0);
    }
    __builtin_amdgcn_s_barrier();   // all waves done reading buf[cur] before next DMA into it
  }
#undef STAGE

  // ---------------- epilogue: stage C-tile in LDS, write coalesced rows ----------------
  int sec = (MODE == 0) ? (mt >> 2) : 0;       // 0=Q 1=K 2=V (uniform per block)
  int ow0 = (mt & 3) * 128;
#pragma unroll
  for (int m = 0; m < 4; ++m) {
#pragma unroll
    for (int n = 0; n < 2; ++n) {
#pragma unroll
      for (int r = 0; r < 4; ++r) {
        int o_l = wm * 64 + m * 16 + ((lane >> 4) * 4) + r;   // local out-row
        int l_l = wn * 32 + n * 16 + (lane & 15);             // local l
        float v = acc[m][n][r] + bias[mt * 128 + o_l];
        if (MODE == 0) {
          if (sec == 0) v *= 0.18033688f;   // 0.125 * log2(e): scores in exp2 domain
          u16 bv = f2bf(v);
          if (sec < 2) sm.c16[l_l * 136 + o_l] = bv;   // Q/K: [l][o]
          else         sm.c16[o_l * 136 + l_l] = bv;   // V:   [o][l]
        } else {
          sm.c32[o_l * 128 + l_l] = v;                 // proj: [o][l]
        }
      }
    }
  }
  __syncthreads();
  if (MODE == 0) {
    u16* dst = (sec == 0) ? Qb : (sec == 1 ? Kb : Vb);
#pragma unroll
    for (int p = 0; p < 4; ++p) {
      int row = p * 32 + (tid >> 4);        // 32 rows per pass
      int col = (tid & 15) * 8;             // 16 lanes x 16B = 256B contiguous per row
      u16x8 vv = *reinterpret_cast<const u16x8*>(&sm.c16[row * 136 + col]);
      size_t gi;
      if (sec < 2) gi = ((size_t)(b * 1024 + nt * 128 + row)) * 512 + ow0 + col;
      else         gi = ((size_t)(b * 512 + ow0 + row)) * 1024 + nt * 128 + col;
      *reinterpret_cast<u16x8*>(dst + gi) = vv;
    }
  } else {
#pragma unroll
    for (int p = 0; p < 8; ++p) {
      int row = p * 16 + (tid >> 5);        // 16 rows per pass
      int col = (tid & 31) * 4;             // 32 lanes x 16B = 512B contiguous per row
      float4 vv = *reinterpret_cast<const float4*>(&sm.c32[row * 128 + col]);
      size_t gi = ((size_t)(b * 512 + mt * 128 + row)) * 1024 + nt * 128 + col;
      float4 xr = *reinterpret_cast<const float4*>(xres + gi);
      vv.x += xr.x; vv.y += xr.y; vv.z += xr.z; vv.w += xr.w;
      *reinterpret_cast<float4*>(out + gi) = vv;
    }
  }
}

// ---------------- flash attention, swapped-QK 32x32 in-register softmax ----------------
__global__ __launch_bounds__(256) void k_attn(
    const u16* __restrict__ Qb, const u16* __restrict__ Kb,
    const u16* __restrict__ Vb, u16* __restrict__ OT) {
  int b = blockIdx.x & 7;
  int h = (blockIdx.x >> 3) & 7;
  int qt = blockIdx.x >> 6;
  int tid = threadIdx.x;
  int lane = tid & 63, wid = tid >> 6;
  int l31 = lane & 31, g = lane >> 5;
  int r7 = l31 & 7;
  __shared__ u16 Ks[64 * 64], Vs[64 * 64];

  short8 qf[4];
  int qrow = qt * 128 + wid * 32 + l31;
  const u16* qp = Qb + ((size_t)(b * 1024 + qrow)) * 512 + h * 64 + g * 8;
#pragma unroll
  for (int kc2 = 0; kc2 < 4; ++kc2)
    qf[kc2] = *reinterpret_cast<const short8*>(qp + kc2 * 16);

  floatx16 oacc[2];
#pragma unroll
  for (int nd = 0; nd < 2; ++nd)
#pragma unroll
    for (int r = 0; r < 16; ++r) oacc[nd][r] = 0.f;
  float m = -1e30f, se = 0.f;

  const u16* ksrc[2]; const u16* vsrc[2]; int sdst[2];
#pragma unroll
  for (int i = 0; i < 2; ++i) {
    int idx = tid + i * 256;
    int row = idx >> 3, cb = idx & 7;
    ksrc[i] = Kb + ((size_t)(b * 1024 + row)) * 512 + h * 64 + cb * 8;
    vsrc[i] = Vb + ((size_t)(b * 512 + h * 64 + row)) * 1024 + cb * 8;
    sdst[i] = row * 64 + ((cb ^ (row & 7)) * 8);
  }
  short8 kreg[2], vreg[2];
#pragma unroll
  for (int i = 0; i < 2; ++i) {
    kreg[i] = *reinterpret_cast<const short8*>(ksrc[i]);
    vreg[i] = *reinterpret_cast<const short8*>(vsrc[i]);
  }

  for (int kt = 0; kt < 16; ++kt) {
#pragma unroll
    for (int i = 0; i < 2; ++i) {
      *reinterpret_cast<short8*>(Ks + sdst[i]) = kreg[i];
      *reinterpret_cast<short8*>(Vs + sdst[i]) = vreg[i];
    }
    __syncthreads();
    if (kt < 15) {
#pragma unroll
      for (int i = 0; i < 2; ++i) {
        kreg[i] = *reinterpret_cast<const short8*>(ksrc[i] + (size_t)(kt + 1) * 64 * 512);
        vreg[i] = *reinterpret_cast<const short8*>(vsrc[i] + (kt + 1) * 64);
      }
    }
    floatx16 sacc[2];
#pragma unroll
    for (int nk = 0; nk < 2; ++nk)
#pragma unroll
      for (int r = 0; r < 16; ++r) sacc[nk][r] = 0.f;
#pragma unroll
    for (int nk = 0; nk < 2; ++nk) {
      const u16* krow = Ks + (nk * 32 + l31) * 64;
#pragma unroll
      for (int kc2 = 0; kc2 < 4; ++kc2) {
        int cb = kc2 * 2 + g;
        short8 kf = *reinterpret_cast<const short8*>(krow + ((cb ^ r7) * 8));
        sacc[nk] = __builtin_amdgcn_mfma_f32_32x32x16_bf16(kf, qf[kc2], sacc[nk], 0, 0, 0);
      }
    }
    float pmax = sacc[0][0];
#pragma unroll
    for (int r = 1; r < 16; ++r) pmax = fmaxf(pmax, sacc[0][r]);
#pragma unroll
    for (int r = 0; r < 16; ++r) pmax = fmaxf(pmax, sacc[1][r]);
    pmax = fmaxf(pmax, __shfl_xor(pmax, 32));
    if (__any(pmax > m + 8.0f)) {      // defer-max
      float mn = fmaxf(m, pmax);
      float f = __builtin_amdgcn_exp2f(m - mn);
      m = mn;
      se *= f;
#pragma unroll
      for (int nd = 0; nd < 2; ++nd)
#pragma unroll
        for (int r = 0; r < 16; ++r) oacc[nd][r] *= f;
    }
    float sum = 0.f;
#pragma unroll
    for (int nk = 0; nk < 2; ++nk)
#pragma unroll
      for (int r = 0; r < 16; ++r) {
        float pv = __builtin_amdgcn_exp2f(sacc[nk][r] - m);
        sacc[nk][r] = pv;
        sum += pv;
      }
    sum += __shfl_xor(sum, 32);
    se += sum;
#pragma unroll
    for (int nk = 0; nk < 2; ++nk) {
#pragma unroll
      for (int kc = 0; kc < 2; ++kc) {
        int base = kc * 8;
        unsigned w0 = cvt_pk_bf16(sacc[nk][base + 0], sacc[nk][base + 1]);
        unsigned w2 = cvt_pk_bf16(sacc[nk][base + 4], sacc[nk][base + 5]);
        auto s0 = __builtin_amdgcn_permlane32_swap((int)w0, (int)w2, false, false);
        unsigned w1 = cvt_pk_bf16(sacc[nk][base + 2], sacc[nk][base + 3]);
        unsigned w3 = cvt_pk_bf16(sacc[nk][base + 6], sacc[nk][base + 7]);
        auto s1 = __builtin_amdgcn_permlane32_swap((int)w1, (int)w3, false, false);
        short8 pf = __builtin_bit_cast(short8,
            uint4v{(unsigned)s0[0], (unsigned)s1[0], (unsigned)s0[1], (unsigned)s1[1]});
#pragma unroll
        for (int nd = 0; nd < 2; ++nd) {
          const u16* vrow = Vs + (nd * 32 + l31) * 64;
          int cb = nk * 4 + kc * 2 + g;
          short8 vf = *reinterpret_cast<const short8*>(vrow + ((cb ^ r7) * 8));
          oacc[nd] = __builtin_amdgcn_mfma_f32_32x32x16_bf16(vf, pf, oacc[nd], 0, 0, 0);
        }
      }
    }
    __syncthreads();
  }
  float inv = 1.0f / se;
  u16* obase = OT + ((size_t)(b * 1024 + qrow)) * 512 + h * 64;
#pragma unroll
  for (int nd = 0; nd < 2; ++nd) {
#pragma unroll
    for (int rq = 0; rq < 4; ++rq) {
      u16x4 o = { f2bf(oacc[nd][rq * 4 + 0] * inv), f2bf(oacc[nd][rq * 4 + 1] * inv),
                  f2bf(oacc[nd][rq * 4 + 2] * inv), f2bf(oacc[nd][rq * 4 + 3] * inv) };
      *reinterpret_cast<u16x4*>(obase + nd * 32 + rq * 8 + g * 4) = o;
    }
  }
}

extern "C" void kernel_launch(void* const* d_in, const int* in_sizes, int n_in,
                              void* d_out, int out_size, void* d_ws, size_t ws_size,
                              hipStream_t stream) {
  const float* x      = (const float*)d_in[0];
  const float* gamma  = (const float*)d_in[1];
  const float* beta   = (const float*)d_in[2];
  const float* w_qkv  = (const float*)d_in[3];
  const float* b_qkv  = (const float*)d_in[4];
  const float* w_proj = (const float*)d_in[5];
  const float* b_proj = (const float*)d_in[6];
  float* out = (float*)d_out;

  char* ws = (char*)d_ws;
  size_t off = 0;
  float* stats = (float*)(ws + off); off += 4096;
  u16* wqb = (u16*)(ws + off); off += (size_t)1536 * 512 * 2;
  u16* wpb = (u16*)(ws + off); off += (size_t)512 * 512 * 2;
  u16* xnT = (u16*)(ws + off); off += (size_t)8 * 1024 * 512 * 2;
  u16* Qb  = (u16*)(ws + off); off += (size_t)8 * 1024 * 512 * 2;
  u16* Kb  = (u16*)(ws + off); off += (size_t)8 * 1024 * 512 * 2;
  u16* Vb  = (u16*)(ws + off); off += (size_t)8 * 1024 * 512 * 2;
  u16* OT  = (u16*)(ws + off); off += (size_t)8 * 1024 * 512 * 2;
  if (ws_size < off) return;

  k_convert<<<1024, 256, 0, stream>>>(w_qkv, w_proj, wqb, wpb);
  k_gn_stats<<<512, 256, 0, stream>>>(x, stats);
  k_gn_norm<<<512, 256, 0, stream>>>(x, gamma, beta, stats, xnT);
  k_gemm<0><<<768, 512, 0, stream>>>(wqb, xnT, b_qkv, nullptr, Qb, Kb, Vb, nullptr);
  k_attn<<<512, 256, 0, stream>>>(Qb, Kb, Vb, OT);
  k_gemm<1><<<256, 512, 0, stream>>>(wpb, OT, b_proj, x, nullptr, nullptr, nullptr, out);
}